// Round 10
// baseline (33.487 us; speedup 1.0000x reference)
//
#include <hip/hip_runtime.h>

// Problem constants (from reference): B=32, K=8, H=240, W=320
constexpr int B_  = 32;
constexpr int K_  = 8;
constexpr int H_  = 240;
constexpr int W_  = 320;
constexpr int HW  = H_ * W_;          // 76800
constexpr int NQ  = HW / 4;           // 19200 float4 quads per plane
constexpr int TPB = 64;               // ONE wave per block: no barriers, fine-grain sched
constexpr int NPT = 3;                // quads per thread (pipelined frags)
constexpr int QPB = TPB * NPT;        // 192 quads per block
constexpr int BPB = NQ / QPB;         // 100 blocks/batch -> grid 3200
constexpr int NBLK = B_ * BPB;        // 3200 partials

typedef float f32x4 __attribute__((ext_vector_type(4)));

// Inline-asm load: compiler cannot split/serialize; WE own the vmcnt waits.
#define GLOADX4(dst, ptr) \
    asm volatile("global_load_dwordx4 %0, %1, off" : "=v"(dst) : "v"(ptr))

// Explicit drain + scheduling fence (rule #18: a sched_barrier(0) must follow
// an inline-asm waitcnt or the machine scheduler hoists consumers past it).
#define WAITV(n) \
    do { asm volatile("s_waitcnt vmcnt(" #n ")"); \
         __builtin_amdgcn_sched_barrier(0); } while (0)

struct Frag {
    f32x4 p0, p1, p2;
    f32x4 m[K_];
    f32x4 t0, t1, t2;
};

__device__ __forceinline__ void issue_frag(Frag& F,
                                           const f32x4* __restrict__ Px,
                                           const f32x4* __restrict__ Py,
                                           const f32x4* __restrict__ Pz,
                                           const f32x4* __restrict__ Tx,
                                           const f32x4* __restrict__ Ty,
                                           const f32x4* __restrict__ Tz,
                                           const f32x4* __restrict__ Mb,
                                           int q)
{
    // 14 back-to-back dwordx4 loads, order = consumption order.
    GLOADX4(F.p0, Px + q);
    GLOADX4(F.p1, Py + q);
    GLOADX4(F.p2, Pz + q);
    #pragma unroll
    for (int k = 0; k < K_; ++k) GLOADX4(F.m[k], Mb + (size_t)k * NQ + q);
    GLOADX4(F.t0, Tx + q);
    GLOADX4(F.t1, Ty + q);
    GLOADX4(F.t2, Tz + q);
}

// tf is wave-uniform (global) -> s_load into SGPRs, hoisted.
__device__ __forceinline__ void accum_frag(const Frag& F, const float* __restrict__ tf,
                                           float& acc)
{
    const float px[4] = {F.p0.x, F.p0.y, F.p0.z, F.p0.w};
    const float py[4] = {F.p1.x, F.p1.y, F.p1.z, F.p1.w};
    const float pz[4] = {F.p2.x, F.p2.y, F.p2.z, F.p2.w};

    float prx[4] = {0.f, 0.f, 0.f, 0.f};
    float pry[4] = {0.f, 0.f, 0.f, 0.f};
    float prz[4] = {0.f, 0.f, 0.f, 0.f};

    #pragma unroll
    for (int k = 0; k < K_; ++k) {
        const float f0 = tf[k*12+0], f1 = tf[k*12+1], f2  = tf[k*12+2],  f3  = tf[k*12+3];
        const float f4 = tf[k*12+4], f5 = tf[k*12+5], f6  = tf[k*12+6],  f7  = tf[k*12+7];
        const float f8 = tf[k*12+8], f9 = tf[k*12+9], f10 = tf[k*12+10], f11 = tf[k*12+11];
        const float m[4] = {F.m[k].x, F.m[k].y, F.m[k].z, F.m[k].w};
        #pragma unroll
        for (int l = 0; l < 4; ++l) {
            const float vx = fmaf(f0, px[l], fmaf(f1, py[l], fmaf(f2,  pz[l], f3)));
            const float vy = fmaf(f4, px[l], fmaf(f5, py[l], fmaf(f6,  pz[l], f7)));
            const float vz = fmaf(f8, px[l], fmaf(f9, py[l], fmaf(f10, pz[l], f11)));
            prx[l] = fmaf(m[l], vx, prx[l]);
            pry[l] = fmaf(m[l], vy, pry[l]);
            prz[l] = fmaf(m[l], vz, prz[l]);
        }
    }

    const float tx[4] = {F.t0.x, F.t0.y, F.t0.z, F.t0.w};
    const float ty[4] = {F.t1.x, F.t1.y, F.t1.z, F.t1.w};
    const float tz[4] = {F.t2.x, F.t2.y, F.t2.z, F.t2.w};
    #pragma unroll
    for (int l = 0; l < 4; ++l) {
        const float ex = prx[l] - tx[l];
        const float ey = pry[l] - ty[l];
        const float ez = prz[l] - tz[l];
        acc = fmaf(ex, ex, acc);
        acc = fmaf(ey, ey, acc);
        acc = fmaf(ez, ez, acc);
    }
}

__global__ __launch_bounds__(TPB)
void w3d_loss_kernel(const float* __restrict__ pts,
                     const float* __restrict__ masks,
                     const float* __restrict__ tfms,
                     const float* __restrict__ tgt,
                     const float* __restrict__ numpts,
                     float* __restrict__ partial)
{
    const int b    = blockIdx.x / BPB;
    const int blk  = blockIdx.x % BPB;
    const int lane = (int)threadIdx.x;               // 0..63, one wave
    const int q0   = blk * QPB + lane;

    const f32x4* Px = (const f32x4*)(pts + (size_t)b * 3 * HW);
    const f32x4* Py = Px + NQ;
    const f32x4* Pz = Py + NQ;
    const f32x4* Tx = (const f32x4*)(tgt + (size_t)b * 3 * HW);
    const f32x4* Ty = Tx + NQ;
    const f32x4* Tz = Ty + NQ;
    const f32x4* Mb = (const f32x4*)(masks + (size_t)b * K_ * HW);
    const float* tf = tfms + (size_t)b * K_ * 12;    // wave-uniform -> s_load

    float acc = 0.0f;

    // Pipeline: issue A, issue B (28 out) -> wait(14), compute A,
    // issue C into A's regs (28 out) -> wait(14), compute B -> wait(0), compute C.
    Frag A, Bf;
    issue_frag(A,  Px, Py, Pz, Tx, Ty, Tz, Mb, q0);
    issue_frag(Bf, Px, Py, Pz, Tx, Ty, Tz, Mb, q0 + TPB);
    WAITV(14);
    accum_frag(A, tf, acc);
    issue_frag(A,  Px, Py, Pz, Tx, Ty, Tz, Mb, q0 + 2 * TPB);
    WAITV(14);
    accum_frag(Bf, tf, acc);
    WAITV(0);
    accum_frag(A, tf, acc);

    // Wave-64 butterfly reduce; single wave -> no LDS, no barrier.
    #pragma unroll
    for (int off = 32; off > 0; off >>= 1)
        acc += __shfl_down(acc, off, 64);

    // ONE uncontended store per wave (no same-address atomic chain).
    if (lane == 0)
        partial[blockIdx.x] = 0.5f * acc / numpts[b];
}

// Single-block final reduction of the 3200 partials (L2-resident, ~2 us).
__global__ __launch_bounds__(256)
void w3d_reduce_kernel(const float* __restrict__ partial, float* __restrict__ out)
{
    float s = 0.f;
    for (int i = (int)threadIdx.x; i < NBLK; i += 256)
        s += partial[i];

    #pragma unroll
    for (int off = 32; off > 0; off >>= 1)
        s += __shfl_down(s, off, 64);

    __shared__ float wsum[4];
    const int wid  = threadIdx.x >> 6;
    const int lane = threadIdx.x & 63;
    if (lane == 0) wsum[wid] = s;
    __syncthreads();

    if (threadIdx.x == 0)
        out[0] = wsum[0] + wsum[1] + wsum[2] + wsum[3];
}

extern "C" void kernel_launch(void* const* d_in, const int* in_sizes, int n_in,
                              void* d_out, int out_size, void* d_ws, size_t ws_size,
                              hipStream_t stream)
{
    const float* pts    = (const float*)d_in[0];
    const float* masks  = (const float*)d_in[1];
    const float* tfms   = (const float*)d_in[2];
    const float* tgt    = (const float*)d_in[3];
    const float* numpts = (const float*)d_in[4];
    float* out     = (float*)d_out;
    float* partial = (float*)d_ws;   // 3200 floats, fully written every call

    w3d_loss_kernel<<<dim3(NBLK), dim3(TPB), 0, stream>>>(
        pts, masks, tfms, tgt, numpts, partial);
    w3d_reduce_kernel<<<dim3(1), dim3(256), 0, stream>>>(partial, out);
}

// Round 11
// 28.579 us; speedup vs baseline: 1.1718x; 1.1718x over previous
//
#include <hip/hip_runtime.h>

// Problem constants (from reference): B=32, K=8, H=240, W=320
constexpr int B_  = 32;
constexpr int K_  = 8;
constexpr int H_  = 240;
constexpr int W_  = 320;
constexpr int HW  = H_ * W_;          // 76800
constexpr int NQ  = HW / 4;           // 19200 float4 quads per plane
constexpr int TPB = 256;              // threads per block
constexpr int NPT = 5;                // quads per thread (deep rolling pipeline)
constexpr int QPB = TPB * NPT;        // 1280 quads per block
constexpr int BPB = NQ / QPB;         // 15 blocks/batch -> grid 480 (co-resident, 2/CU)
constexpr int NBLK = B_ * BPB;        // 480 partials

typedef float f32x4 __attribute__((ext_vector_type(4)));

// Inline-asm load: compiler cannot split/serialize; WE own the vmcnt waits.
#define GLOADX4(dst, ptr) \
    asm volatile("global_load_dwordx4 %0, %1, off" : "=v"(dst) : "v"(ptr))

// Explicit drain + scheduling fence (rule #18: a sched_barrier(0) must follow
// an inline-asm waitcnt or the machine scheduler hoists consumers past it).
#define WAITV(n) \
    do { asm volatile("s_waitcnt vmcnt(" #n ")"); \
         __builtin_amdgcn_sched_barrier(0); } while (0)

struct Frag {
    f32x4 p0, p1, p2;
    f32x4 m[K_];
    f32x4 t0, t1, t2;
};

__device__ __forceinline__ void issue_frag(Frag& F,
                                           const f32x4* __restrict__ Px,
                                           const f32x4* __restrict__ Py,
                                           const f32x4* __restrict__ Pz,
                                           const f32x4* __restrict__ Tx,
                                           const f32x4* __restrict__ Ty,
                                           const f32x4* __restrict__ Tz,
                                           const f32x4* __restrict__ Mb,
                                           int q)
{
    // 14 back-to-back dwordx4 loads, order = consumption order.
    GLOADX4(F.p0, Px + q);
    GLOADX4(F.p1, Py + q);
    GLOADX4(F.p2, Pz + q);
    #pragma unroll
    for (int k = 0; k < K_; ++k) GLOADX4(F.m[k], Mb + (size_t)k * NQ + q);
    GLOADX4(F.t0, Tx + q);
    GLOADX4(F.t1, Ty + q);
    GLOADX4(F.t2, Tz + q);
}

// tf is wave-uniform (global) -> s_load into SGPRs, hoisted.
__device__ __forceinline__ void accum_frag(const Frag& F, const float* __restrict__ tf,
                                           float& acc)
{
    const float px[4] = {F.p0.x, F.p0.y, F.p0.z, F.p0.w};
    const float py[4] = {F.p1.x, F.p1.y, F.p1.z, F.p1.w};
    const float pz[4] = {F.p2.x, F.p2.y, F.p2.z, F.p2.w};

    float prx[4] = {0.f, 0.f, 0.f, 0.f};
    float pry[4] = {0.f, 0.f, 0.f, 0.f};
    float prz[4] = {0.f, 0.f, 0.f, 0.f};

    #pragma unroll
    for (int k = 0; k < K_; ++k) {
        const float f0 = tf[k*12+0], f1 = tf[k*12+1], f2  = tf[k*12+2],  f3  = tf[k*12+3];
        const float f4 = tf[k*12+4], f5 = tf[k*12+5], f6  = tf[k*12+6],  f7  = tf[k*12+7];
        const float f8 = tf[k*12+8], f9 = tf[k*12+9], f10 = tf[k*12+10], f11 = tf[k*12+11];
        const float m[4] = {F.m[k].x, F.m[k].y, F.m[k].z, F.m[k].w};
        #pragma unroll
        for (int l = 0; l < 4; ++l) {
            const float vx = fmaf(f0, px[l], fmaf(f1, py[l], fmaf(f2,  pz[l], f3)));
            const float vy = fmaf(f4, px[l], fmaf(f5, py[l], fmaf(f6,  pz[l], f7)));
            const float vz = fmaf(f8, px[l], fmaf(f9, py[l], fmaf(f10, pz[l], f11)));
            prx[l] = fmaf(m[l], vx, prx[l]);
            pry[l] = fmaf(m[l], vy, pry[l]);
            prz[l] = fmaf(m[l], vz, prz[l]);
        }
    }

    const float tx[4] = {F.t0.x, F.t0.y, F.t0.z, F.t0.w};
    const float ty[4] = {F.t1.x, F.t1.y, F.t1.z, F.t1.w};
    const float tz[4] = {F.t2.x, F.t2.y, F.t2.z, F.t2.w};
    #pragma unroll
    for (int l = 0; l < 4; ++l) {
        const float ex = prx[l] - tx[l];
        const float ey = pry[l] - ty[l];
        const float ez = prz[l] - tz[l];
        acc = fmaf(ex, ex, acc);
        acc = fmaf(ey, ey, acc);
        acc = fmaf(ez, ez, acc);
    }
}

__global__ __launch_bounds__(TPB, 2)
void w3d_loss_kernel(const float* __restrict__ pts,
                     const float* __restrict__ masks,
                     const float* __restrict__ tfms,
                     const float* __restrict__ tgt,
                     const float* __restrict__ numpts,
                     float* __restrict__ partial)
{
    const int b   = blockIdx.x / BPB;
    const int blk = blockIdx.x % BPB;
    const int q0  = blk * QPB + (int)threadIdx.x;

    const f32x4* Px = (const f32x4*)(pts + (size_t)b * 3 * HW);
    const f32x4* Py = Px + NQ;
    const f32x4* Pz = Py + NQ;
    const f32x4* Tx = (const f32x4*)(tgt + (size_t)b * 3 * HW);
    const f32x4* Ty = Tx + NQ;
    const f32x4* Tz = Ty + NQ;
    const f32x4* Mb = (const f32x4*)(masks + (size_t)b * K_ * HW);
    const float* tf = tfms + (size_t)b * K_ * 12;   // wave-uniform -> s_load

    float acc = 0.0f;

    // Rolling 2-frag pipeline over 5 frags: steady-state 28 loads in flight.
    // Static A/B rotation (no runtime-indexed frag state, rule #20):
    //   issue f0->A, f1->B | wait(14) compute A, f2->A | wait(14) compute B,
    //   f3->B | wait(14) compute A, f4->A | wait(14) compute B | wait(0) compute A.
    Frag A, Bf;
    issue_frag(A,  Px, Py, Pz, Tx, Ty, Tz, Mb, q0 + 0 * TPB);
    issue_frag(Bf, Px, Py, Pz, Tx, Ty, Tz, Mb, q0 + 1 * TPB);
    WAITV(14);
    accum_frag(A, tf, acc);
    issue_frag(A,  Px, Py, Pz, Tx, Ty, Tz, Mb, q0 + 2 * TPB);
    WAITV(14);
    accum_frag(Bf, tf, acc);
    issue_frag(Bf, Px, Py, Pz, Tx, Ty, Tz, Mb, q0 + 3 * TPB);
    WAITV(14);
    accum_frag(A, tf, acc);
    issue_frag(A,  Px, Py, Pz, Tx, Ty, Tz, Mb, q0 + 4 * TPB);
    WAITV(14);
    accum_frag(Bf, tf, acc);
    WAITV(0);
    accum_frag(A, tf, acc);

    // Wave-64 butterfly reduce
    #pragma unroll
    for (int off = 32; off > 0; off >>= 1)
        acc += __shfl_down(acc, off, 64);

    __shared__ float wsum[TPB / 64];
    const int wid  = threadIdx.x >> 6;
    const int lane = threadIdx.x & 63;
    if (lane == 0) wsum[wid] = acc;
    __syncthreads();

    // ONE uncontended store per block (no same-address atomic chain).
    if (threadIdx.x == 0) {
        float s = 0.f;
        #pragma unroll
        for (int w = 0; w < TPB / 64; ++w) s += wsum[w];
        partial[blockIdx.x] = 0.5f * s / numpts[b];
    }
}

// Single-block final reduction of the 480 partials (L2-resident, ~2 us).
__global__ __launch_bounds__(256)
void w3d_reduce_kernel(const float* __restrict__ partial, float* __restrict__ out)
{
    float s = 0.f;
    for (int i = (int)threadIdx.x; i < NBLK; i += 256)
        s += partial[i];

    #pragma unroll
    for (int off = 32; off > 0; off >>= 1)
        s += __shfl_down(s, off, 64);

    __shared__ float wsum[4];
    const int wid  = threadIdx.x >> 6;
    const int lane = threadIdx.x & 63;
    if (lane == 0) wsum[wid] = s;
    __syncthreads();

    if (threadIdx.x == 0)
        out[0] = wsum[0] + wsum[1] + wsum[2] + wsum[3];
}

extern "C" void kernel_launch(void* const* d_in, const int* in_sizes, int n_in,
                              void* d_out, int out_size, void* d_ws, size_t ws_size,
                              hipStream_t stream)
{
    const float* pts    = (const float*)d_in[0];
    const float* masks  = (const float*)d_in[1];
    const float* tfms   = (const float*)d_in[2];
    const float* tgt    = (const float*)d_in[3];
    const float* numpts = (const float*)d_in[4];
    float* out     = (float*)d_out;
    float* partial = (float*)d_ws;   // 480 floats, fully written every call

    w3d_loss_kernel<<<dim3(NBLK), dim3(TPB), 0, stream>>>(
        pts, masks, tfms, tgt, numpts, partial);
    w3d_reduce_kernel<<<dim3(1), dim3(256), 0, stream>>>(partial, out);
}